// Round 1
// baseline (2649.440 us; speedup 1.0000x reference)
//
#include <hip/hip_runtime.h>
#include <math.h>

#define B_ 512
#define S_ 500
#define NQ1_ 10001
#define NQA1_ 20001

// ---------------------------------------------------------------------------
// Generic small transpose: dst[c*rows + r] = src[r*src_ld + src_off + c]
// ---------------------------------------------------------------------------
__global__ void transpose_kernel(const float* __restrict__ src, float* __restrict__ dst,
                                 int rows, int cols, int src_ld, int src_off) {
    int idx = blockIdx.x * 256 + threadIdx.x;
    if (idx < rows * cols) {
        int r = idx / cols, c = idx % cols;
        dst[c * rows + r] = src[r * src_ld + src_off + c];
    }
}

// ---------------------------------------------------------------------------
// Per-q-index precompute: Wsm = softmax(q@Mk.T), Sq = q@Ws_q.T, dq = tanh(q@Wd+bd)
// 8 q rows per block, 128 threads (thread j = output column j).
// ---------------------------------------------------------------------------
__global__ __launch_bounds__(128) void kq_kernel(
    const float* __restrict__ q_embed, const float* __restrict__ MkT,
    const float* __restrict__ WsqT, const float* __restrict__ Wd,
    const float* __restrict__ bdp,
    float* __restrict__ Wsm, float* __restrict__ Sq, float* __restrict__ dqv)
{
    int i0 = blockIdx.x * 8;
    int j = threadIdx.x;
    int lane = j & 63, wv = j >> 6;
    __shared__ float qlds[8][128];
    __shared__ float xred[2];

#pragma unroll
    for (int r = 0; r < 8; ++r) {
        int i = i0 + r;
        qlds[r][j] = (i < NQ1_) ? q_embed[i * 128 + j] : 0.f;
    }
    __syncthreads();

    float lg[8], sq[8];
#pragma unroll
    for (int r = 0; r < 8; ++r) { lg[r] = 0.f; sq[r] = 0.f; }

    for (int k = 0; k < 128; ++k) {
        float mk = MkT[k * 128 + j];
        float ws = WsqT[k * 128 + j];
#pragma unroll
        for (int r = 0; r < 8; ++r) {
            float qv = qlds[r][k];
            lg[r] = fmaf(qv, mk, lg[r]);
            sq[r] = fmaf(qv, ws, sq[r]);
        }
    }

    float wdj = Wd[j];
    float bd = bdp[0];

    for (int r = 0; r < 8; ++r) {
        int i = i0 + r;
        // max-reduce over 128 threads (2 waves)
        float m = lg[r];
        for (int off = 32; off; off >>= 1) m = fmaxf(m, __shfl_xor(m, off));
        if (lane == 0) xred[wv] = m;
        __syncthreads();
        m = fmaxf(xred[0], xred[1]);
        __syncthreads();
        float ex = expf(lg[r] - m);
        float s = ex;
        for (int off = 32; off; off >>= 1) s += __shfl_xor(s, off);
        if (lane == 0) xred[wv] = s;
        __syncthreads();
        s = xred[0] + xred[1];
        __syncthreads();
        if (i < NQ1_) {
            Wsm[i * 128 + j] = ex / s;
            Sq[i * 128 + j] = sq[r];
        }
        // dq: sum over k of q[k]*Wd[k] (thread j contributes k=j)
        float dd = qlds[r][j] * wdj;
        for (int off = 32; off; off >>= 1) dd += __shfl_xor(dd, off);
        if (lane == 0) xred[wv] = dd;
        __syncthreads();
        if (j == 0 && i < NQ1_) dqv[i] = tanhf(xred[0] + xred[1] + bd);
        __syncthreads();
    }
}

// ---------------------------------------------------------------------------
// Per-qa-index precompute: E = sigmoid(qa@We.T+be), A = tanh(qa@Wa.T+ba)
// 8 qa rows per block, 256 threads (thread d = output column d).
// ---------------------------------------------------------------------------
__global__ __launch_bounds__(256) void kqa_kernel(
    const float* __restrict__ qa_embed, const float* __restrict__ WeT,
    const float* __restrict__ WaT, const float* __restrict__ be,
    const float* __restrict__ ba,
    float* __restrict__ E, float* __restrict__ A)
{
    int i0 = blockIdx.x * 8;
    int d = threadIdx.x;
    __shared__ float qlds[8][256];

#pragma unroll
    for (int r = 0; r < 8; ++r) {
        int i = i0 + r;
        qlds[r][d] = (i < NQA1_) ? qa_embed[i * 256 + d] : 0.f;
    }
    __syncthreads();

    float zE[8], zA[8];
    float beD = be[d], baD = ba[d];
#pragma unroll
    for (int r = 0; r < 8; ++r) { zE[r] = beD; zA[r] = baD; }

    for (int k = 0; k < 256; ++k) {
        float we = WeT[k * 256 + d];
        float wa = WaT[k * 256 + d];
#pragma unroll
        for (int r = 0; r < 8; ++r) {
            float qv = qlds[r][k];
            zE[r] = fmaf(qv, we, zE[r]);
            zA[r] = fmaf(qv, wa, zA[r]);
        }
    }
#pragma unroll
    for (int r = 0; r < 8; ++r) {
        int i = i0 + r;
        if (i < NQA1_) {
            E[i * 256 + d] = 1.f / (1.f + expf(-zE[r]));
            A[i * 256 + d] = tanhf(zA[r]);
        }
    }
}

// ---------------------------------------------------------------------------
// Main recurrence. One block per batch row b. 512 threads.
// Mv in registers: thread (h = tid>>8, d = tid&255) owns Mv[h*64 + i][d], i<64.
// Ws_r slice in registers: thread (seg = tid>>7, j = tid&127) owns
// WsrT[seg*64+dd][j], dd<64.
// w/e/a/Sq/dq rows double-buffered in LDS with register-staged prefetch.
// ---------------------------------------------------------------------------
__global__ __launch_bounds__(512) void rec_kernel(
    const int* __restrict__ q_data, const int* __restrict__ qa_data,
    const float* __restrict__ Mv0,
    const float* __restrict__ Wsm, const float* __restrict__ Sq,
    const float* __restrict__ dqv,
    const float* __restrict__ E, const float* __restrict__ A,
    const float* __restrict__ WsrT, const float* __restrict__ bs,
    const float* __restrict__ Wab, const float* __restrict__ bab,
    float* __restrict__ out)
{
    const int b = blockIdx.x;
    const int tid = threadIdx.x;
    const int h = tid >> 8;       // 0..1 : m-half
    const int d = tid & 255;      // memory column
    const int j = tid & 127;      // summary index
    const int seg = tid >> 7;     // 0..3 : d-quarter for z matmul

    __shared__ __align__(16) float wbuf[2][128];
    __shared__ __align__(16) float ebuf[2][256];
    __shared__ __align__(16) float abuf[2][256];
    __shared__ __align__(16) float sqbuf[2][128];
    __shared__ float dqbuf[2];
    __shared__ __align__(16) float rbuf[2][256];
    __shared__ float zpart[4][128];
    __shared__ float sred[128];

    // Ws_r slice -> registers (coalesced via WsrT)
    float wsreg[64];
#pragma unroll
    for (int dd = 0; dd < 64; ++dd)
        wsreg[dd] = WsrT[(seg * 64 + dd) * 128 + j];

    // Mv -> registers (coalesced: consecutive d per lane)
    float Mv[64];
#pragma unroll
    for (int i = 0; i < 64; ++i)
        Mv[i] = Mv0[(h * 64 + i) * 256 + d];

    const float bs_j = bs[j];
    const float wab_j = Wab[j];
    const float bab_v = bab[0];
    const int BS = B_ * S_;

    // prologue: stage t=0 into slot 0
    {
        int qid = q_data[b * S_];
        int qaid = qa_data[b * S_];
        if (tid < 128) {
            wbuf[0][tid] = Wsm[qid * 128 + tid];
            if (tid == 0) dqbuf[0] = dqv[qid];
        } else if (tid < 256) {
            sqbuf[0][tid - 128] = Sq[qid * 128 + (tid - 128)];
        } else {
            int dd2 = tid - 256;
            ebuf[0][dd2] = E[qaid * 256 + dd2];
            abuf[0][dd2] = A[qaid * 256 + dd2];
        }
    }
    __syncthreads();

    for (int t = 0; t < S_; ++t) {
        const int cur = t & 1, nxt = cur ^ 1;

        // ---- issue prefetch for t+1 into registers (write to LDS later) ----
        float pf0 = 0.f, pf1 = 0.f;
        const bool havepf = (t + 1 < S_);
        if (havepf) {
            int qid = q_data[b * S_ + t + 1];
            int qaid = qa_data[b * S_ + t + 1];
            if (tid < 128) {
                pf0 = Wsm[qid * 128 + tid];
                if (tid == 0) pf1 = dqv[qid];
            } else if (tid < 256) {
                pf0 = Sq[qid * 128 + (tid - 128)];
            } else {
                int dd2 = tid - 256;
                pf0 = E[qaid * 256 + dd2];
                pf1 = A[qaid * 256 + dd2];
            }
        }

        // ---- P1: read partial + Mv update (old Mv used for both) ----
        const float e_d = ebuf[cur][d];
        const float na = -abuf[cur][d];
        float rp0 = 0.f, rp1 = 0.f, rp2 = 0.f, rp3 = 0.f;
        const float* wrow = &wbuf[cur][h << 6];
#pragma unroll
        for (int i4 = 0; i4 < 16; ++i4) {
            float4 w4 = *reinterpret_cast<const float4*>(wrow + (i4 << 2));
            float mv, t1;
            mv = Mv[4 * i4 + 0]; t1 = fmaf(e_d, mv, na); rp0 = fmaf(w4.x, mv, rp0); Mv[4 * i4 + 0] = fmaf(-w4.x, t1, mv);
            mv = Mv[4 * i4 + 1]; t1 = fmaf(e_d, mv, na); rp1 = fmaf(w4.y, mv, rp1); Mv[4 * i4 + 1] = fmaf(-w4.y, t1, mv);
            mv = Mv[4 * i4 + 2]; t1 = fmaf(e_d, mv, na); rp2 = fmaf(w4.z, mv, rp2); Mv[4 * i4 + 2] = fmaf(-w4.z, t1, mv);
            mv = Mv[4 * i4 + 3]; t1 = fmaf(e_d, mv, na); rp3 = fmaf(w4.w, mv, rp3); Mv[4 * i4 + 3] = fmaf(-w4.w, t1, mv);
        }
        rbuf[h][d] = (rp0 + rp1) + (rp2 + rp3);
        __syncthreads();   // B1

        // ---- P3: z[j] partial = sum over this seg's 64 d of read[d]*Ws_r ----
        {
            const float4* rb0 = reinterpret_cast<const float4*>(&rbuf[0][seg << 6]);
            const float4* rb1 = reinterpret_cast<const float4*>(&rbuf[1][seg << 6]);
            float a0 = 0.f, a1 = 0.f, a2 = 0.f, a3 = 0.f;
#pragma unroll
            for (int i4 = 0; i4 < 16; ++i4) {
                float4 r0 = rb0[i4];
                float4 r1 = rb1[i4];
                a0 = fmaf(r0.x + r1.x, wsreg[4 * i4 + 0], a0);
                a1 = fmaf(r0.y + r1.y, wsreg[4 * i4 + 1], a1);
                a2 = fmaf(r0.z + r1.z, wsreg[4 * i4 + 2], a2);
                a3 = fmaf(r0.w + r1.w, wsreg[4 * i4 + 3], a3);
            }
            zpart[seg][j] = (a0 + a1) + (a2 + a3);
        }
        __syncthreads();   // B2

        // ---- P4: summary + weighted terms; P6: write prefetch to LDS ----
        if (tid < 128) {
            float z = ((zpart[0][tid] + zpart[1][tid]) + (zpart[2][tid] + zpart[3][tid]))
                      + sqbuf[cur][tid] + bs_j;
            float s = tanhf(z);
            sred[tid] = s * wab_j;
            if (havepf) {
                wbuf[nxt][tid] = pf0;
                if (tid == 0) dqbuf[nxt] = pf1;
            }
        } else if (tid < 256) {
            if (havepf) sqbuf[nxt][tid - 128] = pf0;
        } else {
            if (havepf) {
                int dd2 = tid - 256;
                ebuf[nxt][dd2] = pf0;
                abuf[nxt][dd2] = pf1;
            }
        }
        __syncthreads();   // B3

        // ---- P5: final reduction + output ----
        if (tid < 64) {
            float v = sred[tid] + sred[tid + 64];
            v += __shfl_xor(v, 32);
            v += __shfl_xor(v, 16);
            v += __shfl_xor(v, 8);
            v += __shfl_xor(v, 4);
            v += __shfl_xor(v, 2);
            v += __shfl_xor(v, 1);
            if (tid == 0) {
                float ability = v + bab_v;
                float diff = dqbuf[cur];
                out[b * S_ + t] = 3.f * ability - diff;
                out[BS + b * S_ + t] = ability;
                out[2 * BS + b * S_ + t] = diff;
            }
        }
        // next iteration's B1 orders P5 vs. next P1's LDS writes
    }
}

// ---------------------------------------------------------------------------
extern "C" void kernel_launch(void* const* d_in, const int* in_sizes, int n_in,
                              void* d_out, int out_size, void* d_ws, size_t ws_size,
                              hipStream_t stream) {
    const int* q_data  = (const int*)d_in[0];
    const int* qa_data = (const int*)d_in[1];
    // d_in[2] = label (unused by reference forward pass)
    const float* Mk       = (const float*)d_in[3];
    const float* Mv0      = (const float*)d_in[4];
    const float* q_embed  = (const float*)d_in[5];
    const float* qa_embed = (const float*)d_in[6];
    const float* We  = (const float*)d_in[7];
    const float* be  = (const float*)d_in[8];
    const float* Wa  = (const float*)d_in[9];
    const float* ba  = (const float*)d_in[10];
    const float* Ws  = (const float*)d_in[11];
    const float* bs  = (const float*)d_in[12];
    const float* Wab = (const float*)d_in[13];
    const float* bab = (const float*)d_in[14];
    const float* Wd  = (const float*)d_in[15];
    const float* bd  = (const float*)d_in[16];
    float* out = (float*)d_out;

    float* ws   = (float*)d_ws;
    float* WeT  = ws;                      // 256*256
    float* WaT  = WeT  + 256 * 256;        // 256*256
    float* MkT  = WaT  + 256 * 256;        // 128*128
    float* WsqT = MkT  + 128 * 128;        // 128*128
    float* WsrT = WsqT + 128 * 128;        // 256*128
    float* Wsm  = WsrT + 256 * 128;        // 10001*128
    float* Sq   = Wsm  + NQ1_ * 128;       // 10001*128
    float* dqv  = Sq   + NQ1_ * 128;       // 10016
    float* E    = dqv  + 10016;            // 20001*256
    float* A    = E    + NQA1_ * 256;      // 20001*256

    transpose_kernel<<<(256 * 256 + 255) / 256, 256, 0, stream>>>(We, WeT, 256, 256, 256, 0);
    transpose_kernel<<<(256 * 256 + 255) / 256, 256, 0, stream>>>(Wa, WaT, 256, 256, 256, 0);
    transpose_kernel<<<(128 * 128 + 255) / 256, 256, 0, stream>>>(Mk, MkT, 128, 128, 128, 0);
    transpose_kernel<<<(128 * 128 + 255) / 256, 256, 0, stream>>>(Ws, WsqT, 128, 128, 384, 256);
    transpose_kernel<<<(128 * 256 + 255) / 256, 256, 0, stream>>>(Ws, WsrT, 128, 256, 384, 0);

    kq_kernel<<<(NQ1_ + 7) / 8, 128, 0, stream>>>(q_embed, MkT, WsqT, Wd, bd, Wsm, Sq, dqv);
    kqa_kernel<<<(NQA1_ + 7) / 8, 256, 0, stream>>>(qa_embed, WeT, WaT, be, ba, E, A);

    rec_kernel<<<B_, 512, 0, stream>>>(q_data, qa_data, Mv0, Wsm, Sq, dqv, E, A,
                                       WsrT, bs, Wab, bab, out);
}

// Round 2
// 1844.006 us; speedup vs baseline: 1.4368x; 1.4368x over previous
//
#include <hip/hip_runtime.h>
#include <math.h>

#define B_ 512
#define S_ 500
#define NQ1_ 10001
#define NQA1_ 20001

typedef float v2f __attribute__((ext_vector_type(2)));
static __device__ __forceinline__ v2f pkfma(v2f a, v2f b, v2f c) {
    return __builtin_elementwise_fma(a, b, c);
}

// ---------------------------------------------------------------------------
// Generic small transpose: dst[c*rows + r] = src[r*src_ld + src_off + c]
// ---------------------------------------------------------------------------
__global__ void transpose_kernel(const float* __restrict__ src, float* __restrict__ dst,
                                 int rows, int cols, int src_ld, int src_off) {
    int idx = blockIdx.x * 256 + threadIdx.x;
    if (idx < rows * cols) {
        int r = idx / cols, c = idx % cols;
        dst[c * rows + r] = src[r * src_ld + src_off + c];
    }
}

// ---------------------------------------------------------------------------
// Per-q-index precompute: Wsm = softmax(q@Mk.T), Sq = q@Ws_q.T, dq = tanh(q@Wd+bd)
// ---------------------------------------------------------------------------
__global__ __launch_bounds__(128) void kq_kernel(
    const float* __restrict__ q_embed, const float* __restrict__ MkT,
    const float* __restrict__ WsqT, const float* __restrict__ Wd,
    const float* __restrict__ bdp,
    float* __restrict__ Wsm, float* __restrict__ Sq, float* __restrict__ dqv)
{
    int i0 = blockIdx.x * 8;
    int j = threadIdx.x;
    int lane = j & 63, wv = j >> 6;
    __shared__ float qlds[8][128];
    __shared__ float xred[2];

#pragma unroll
    for (int r = 0; r < 8; ++r) {
        int i = i0 + r;
        qlds[r][j] = (i < NQ1_) ? q_embed[i * 128 + j] : 0.f;
    }
    __syncthreads();

    float lg[8], sq[8];
#pragma unroll
    for (int r = 0; r < 8; ++r) { lg[r] = 0.f; sq[r] = 0.f; }

    for (int k = 0; k < 128; ++k) {
        float mk = MkT[k * 128 + j];
        float ws = WsqT[k * 128 + j];
#pragma unroll
        for (int r = 0; r < 8; ++r) {
            float qv = qlds[r][k];
            lg[r] = fmaf(qv, mk, lg[r]);
            sq[r] = fmaf(qv, ws, sq[r]);
        }
    }

    float wdj = Wd[j];
    float bd = bdp[0];

    for (int r = 0; r < 8; ++r) {
        int i = i0 + r;
        float m = lg[r];
        for (int off = 32; off; off >>= 1) m = fmaxf(m, __shfl_xor(m, off));
        if (lane == 0) xred[wv] = m;
        __syncthreads();
        m = fmaxf(xred[0], xred[1]);
        __syncthreads();
        float ex = expf(lg[r] - m);
        float s = ex;
        for (int off = 32; off; off >>= 1) s += __shfl_xor(s, off);
        if (lane == 0) xred[wv] = s;
        __syncthreads();
        s = xred[0] + xred[1];
        __syncthreads();
        if (i < NQ1_) {
            Wsm[i * 128 + j] = ex / s;
            Sq[i * 128 + j] = sq[r];
        }
        float dd = qlds[r][j] * wdj;
        for (int off = 32; off; off >>= 1) dd += __shfl_xor(dd, off);
        if (lane == 0) xred[wv] = dd;
        __syncthreads();
        if (j == 0 && i < NQ1_) dqv[i] = tanhf(xred[0] + xred[1] + bd);
        __syncthreads();
    }
}

// ---------------------------------------------------------------------------
// Per-qa-index precompute: E = sigmoid(qa@We.T+be), A = tanh(qa@Wa.T+ba)
// ---------------------------------------------------------------------------
__global__ __launch_bounds__(256) void kqa_kernel(
    const float* __restrict__ qa_embed, const float* __restrict__ WeT,
    const float* __restrict__ WaT, const float* __restrict__ be,
    const float* __restrict__ ba,
    float* __restrict__ E, float* __restrict__ A)
{
    int i0 = blockIdx.x * 8;
    int d = threadIdx.x;
    __shared__ float qlds[8][256];

#pragma unroll
    for (int r = 0; r < 8; ++r) {
        int i = i0 + r;
        qlds[r][d] = (i < NQA1_) ? qa_embed[i * 256 + d] : 0.f;
    }
    __syncthreads();

    float zE[8], zA[8];
    float beD = be[d], baD = ba[d];
#pragma unroll
    for (int r = 0; r < 8; ++r) { zE[r] = beD; zA[r] = baD; }

    for (int k = 0; k < 256; ++k) {
        float we = WeT[k * 256 + d];
        float wa = WaT[k * 256 + d];
#pragma unroll
        for (int r = 0; r < 8; ++r) {
            float qv = qlds[r][k];
            zE[r] = fmaf(qv, we, zE[r]);
            zA[r] = fmaf(qv, wa, zA[r]);
        }
    }
#pragma unroll
    for (int r = 0; r < 8; ++r) {
        int i = i0 + r;
        if (i < NQA1_) {
            E[i * 256 + d] = 1.f / (1.f + expf(-zE[r]));
            A[i * 256 + d] = tanhf(zA[r]);
        }
    }
}

// ---------------------------------------------------------------------------
// Main recurrence, software-pipelined: ONE barrier per step.
// Stage schedule at loop index t:
//   prefetch loads row t+1 (registers)       [t <= S-2]
//   P1: Mv update + read partials for step t [t < S]
//   P3: z partials for output t-1            [1 <= t <= S]
//   P4: tanh/summary for output t-2          [2 <= t <= S+1]  (redundant, balanced)
//   P5: final reduce + store output t-3      [3 <= t <= S+2]
//   prefetch-write row t+1 to LDS
//   __syncthreads()
// Packed-fp32 (v_pk_fma_f32) math in P1/P3.
// ---------------------------------------------------------------------------
__global__ __launch_bounds__(512) void rec_kernel(
    const int* __restrict__ q_data, const int* __restrict__ qa_data,
    const float* __restrict__ Mv0,
    const float* __restrict__ Wsm, const float* __restrict__ Sq,
    const float* __restrict__ dqv,
    const float* __restrict__ E, const float* __restrict__ A,
    const float* __restrict__ WsrT, const float* __restrict__ bs,
    const float* __restrict__ Wab, const float* __restrict__ bab,
    float* __restrict__ out)
{
    const int b = blockIdx.x;
    const int tid = threadIdx.x;
    const int h = tid >> 8;       // 0..1 : m-half
    const int d = tid & 255;      // memory column
    const int j = tid & 127;      // summary index
    const int seg = tid >> 7;     // 0..3 : d-quarter for z matmul

    __shared__ __align__(16) float wbuf[2][128];
    __shared__ __align__(16) float ebuf[2][256];
    __shared__ __align__(16) float abuf[2][256];
    __shared__ __align__(16) float rbuf[2][2][256];
    __shared__ __align__(16) float zpart[2][4][128];
    __shared__ __align__(16) float sqring[4][128];
    __shared__ float sred[2][128];
    __shared__ float dqring[8];

    // Ws_r slice -> register pairs (paired over dd)
    v2f ws2[32];
#pragma unroll
    for (int k = 0; k < 32; ++k) {
        ws2[k].x = WsrT[(seg * 64 + 2 * k) * 128 + j];
        ws2[k].y = WsrT[(seg * 64 + 2 * k + 1) * 128 + j];
    }

    // Mv -> register pairs (paired over row index i)
    v2f Mv2[32];
#pragma unroll
    for (int k = 0; k < 32; ++k) {
        Mv2[k].x = Mv0[(h * 64 + 2 * k) * 256 + d];
        Mv2[k].y = Mv0[(h * 64 + 2 * k + 1) * 256 + d];
    }

    const float bs_j = bs[j];
    const float wab_j = Wab[j];
    const float bab_v = bab[0];
    const int BS = B_ * S_;
    const int* qrow = q_data + b * S_;
    const int* qarow = qa_data + b * S_;

    // prologue: stage row 0
    {
        int qid = qrow[0];
        int qaid = qarow[0];
        if (tid < 128) {
            wbuf[0][tid] = Wsm[qid * 128 + tid];
            if (tid == 0) dqring[0] = dqv[qid];
        } else if (tid < 256) {
            sqring[0][tid - 128] = Sq[qid * 128 + (tid - 128)];
        } else {
            ebuf[0][tid - 256] = E[qaid * 256 + (tid - 256)];
        }
        if (tid < 256) abuf[0][tid] = A[qaid * 256 + tid];
    }
    __syncthreads();

    for (int t = 0; t <= S_ + 2; ++t) {
        const int cur = t & 1, prev = cur ^ 1;

        // ---- prefetch row t+1 into registers ----
        float pfA = 0.f, pfB = 0.f, pfD = 0.f;
        const bool hp = (t + 1 < S_);
        if (hp) {
            int qid = qrow[t + 1];
            int qaid = qarow[t + 1];
            if (tid < 128) {
                pfA = Wsm[qid * 128 + tid];
                if (tid == 0) pfD = dqv[qid];
            } else if (tid < 256) {
                pfA = Sq[qid * 128 + (tid - 128)];
            } else {
                pfA = E[qaid * 256 + (tid - 256)];
            }
            if (tid < 256) pfB = A[qaid * 256 + tid];
        }

        // ---- P1: Mv update + read partial (step t) ----
        if (t < S_) {
            const float e_d = ebuf[cur][d];
            const float a_d = abuf[cur][d];
            const v2f ne2 = { -e_d, -e_d };
            const v2f a2 = { a_d, a_d };
            v2f rd0 = { 0.f, 0.f }, rd1 = { 0.f, 0.f };
            const float4* w4p = reinterpret_cast<const float4*>(&wbuf[cur][h << 6]);
#pragma unroll
            for (int i4 = 0; i4 < 16; ++i4) {
                float4 w4 = w4p[i4];
                v2f wA = { w4.x, w4.y };
                v2f wB = { w4.z, w4.w };
                v2f m0 = Mv2[2 * i4];
                v2f m1 = Mv2[2 * i4 + 1];
                v2f t0 = pkfma(ne2, m0, a2);       // a - e*m
                v2f t1 = pkfma(ne2, m1, a2);
                rd0 = pkfma(wA, m0, rd0);          // read += w*m (old m)
                rd1 = pkfma(wB, m1, rd1);
                Mv2[2 * i4]     = pkfma(wA, t0, m0);  // m' = m + w*(a - e*m)
                Mv2[2 * i4 + 1] = pkfma(wB, t1, m1);
            }
            v2f rs = rd0 + rd1;
            rbuf[cur][h][d] = rs.x + rs.y;
        }

        // ---- P3: z partials for output t-1 ----
        if (t >= 1 && t <= S_) {
            const v2f* r0 = reinterpret_cast<const v2f*>(&rbuf[prev][0][seg << 6]);
            const v2f* r1 = reinterpret_cast<const v2f*>(&rbuf[prev][1][seg << 6]);
            v2f acc0 = { 0.f, 0.f }, acc1 = { 0.f, 0.f };
#pragma unroll
            for (int k = 0; k < 32; k += 2) {
                acc0 = pkfma(r0[k] + r1[k], ws2[k], acc0);
                acc1 = pkfma(r0[k + 1] + r1[k + 1], ws2[k + 1], acc1);
            }
            v2f accs = acc0 + acc1;
            zpart[cur][seg][j] = accs.x + accs.y;
        }

        // ---- P4: summary tanh for output t-2 (redundant on all threads) ----
        if (t >= 2 && t <= S_ + 1) {
            float z = ((zpart[prev][0][j] + zpart[prev][1][j])
                     + (zpart[prev][2][j] + zpart[prev][3][j]))
                    + sqring[(t - 2) & 3][j] + bs_j;
            float s = tanhf(z);
            if (seg == 0) sred[cur][j] = s * wab_j;
        }

        // ---- P5: final reduce + store output t-3 ----
        if (t >= 3 && tid < 64) {
            float v = sred[prev][tid] + sred[prev][tid + 64];
            v += __shfl_xor(v, 32);
            v += __shfl_xor(v, 16);
            v += __shfl_xor(v, 8);
            v += __shfl_xor(v, 4);
            v += __shfl_xor(v, 2);
            v += __shfl_xor(v, 1);
            if (tid == 0) {
                int to = t - 3;
                float ability = v + bab_v;
                float diff = dqring[to & 7];
                out[b * S_ + to] = 3.f * ability - diff;
                out[BS + b * S_ + to] = ability;
                out[2 * BS + b * S_ + to] = diff;
            }
        }

        // ---- prefetch-write row t+1 to LDS ----
        if (hp) {
            const int nxt = prev;  // (t+1) & 1
            if (tid < 128) {
                wbuf[nxt][tid] = pfA;
                if (tid == 0) dqring[(t + 1) & 7] = pfD;
            } else if (tid < 256) {
                sqring[(t + 1) & 3][tid - 128] = pfA;
            } else {
                ebuf[nxt][tid - 256] = pfA;
            }
            if (tid < 256) abuf[nxt][tid] = pfB;
        }

        __syncthreads();
    }
}

// ---------------------------------------------------------------------------
extern "C" void kernel_launch(void* const* d_in, const int* in_sizes, int n_in,
                              void* d_out, int out_size, void* d_ws, size_t ws_size,
                              hipStream_t stream) {
    const int* q_data  = (const int*)d_in[0];
    const int* qa_data = (const int*)d_in[1];
    // d_in[2] = label (unused by reference forward pass)
    const float* Mk       = (const float*)d_in[3];
    const float* Mv0      = (const float*)d_in[4];
    const float* q_embed  = (const float*)d_in[5];
    const float* qa_embed = (const float*)d_in[6];
    const float* We  = (const float*)d_in[7];
    const float* be  = (const float*)d_in[8];
    const float* Wa  = (const float*)d_in[9];
    const float* ba  = (const float*)d_in[10];
    const float* Ws  = (const float*)d_in[11];
    const float* bs  = (const float*)d_in[12];
    const float* Wab = (const float*)d_in[13];
    const float* bab = (const float*)d_in[14];
    const float* Wd  = (const float*)d_in[15];
    const float* bd  = (const float*)d_in[16];
    float* out = (float*)d_out;

    float* ws   = (float*)d_ws;
    float* WeT  = ws;                      // 256*256
    float* WaT  = WeT  + 256 * 256;        // 256*256
    float* MkT  = WaT  + 256 * 256;        // 128*128
    float* WsqT = MkT  + 128 * 128;        // 128*128
    float* WsrT = WsqT + 128 * 128;        // 256*128
    float* Wsm  = WsrT + 256 * 128;        // 10001*128
    float* Sq   = Wsm  + NQ1_ * 128;       // 10001*128
    float* dqv  = Sq   + NQ1_ * 128;       // 10016
    float* E    = dqv  + 10016;            // 20001*256
    float* A    = E    + NQA1_ * 256;      // 20001*256

    transpose_kernel<<<(256 * 256 + 255) / 256, 256, 0, stream>>>(We, WeT, 256, 256, 256, 0);
    transpose_kernel<<<(256 * 256 + 255) / 256, 256, 0, stream>>>(Wa, WaT, 256, 256, 256, 0);
    transpose_kernel<<<(128 * 128 + 255) / 256, 256, 0, stream>>>(Mk, MkT, 128, 128, 128, 0);
    transpose_kernel<<<(128 * 128 + 255) / 256, 256, 0, stream>>>(Ws, WsqT, 128, 128, 384, 256);
    transpose_kernel<<<(128 * 256 + 255) / 256, 256, 0, stream>>>(Ws, WsrT, 128, 256, 384, 0);

    kq_kernel<<<(NQ1_ + 7) / 8, 128, 0, stream>>>(q_embed, MkT, WsqT, Wd, bd, Wsm, Sq, dqv);
    kqa_kernel<<<(NQA1_ + 7) / 8, 256, 0, stream>>>(qa_embed, WeT, WaT, be, ba, E, A);

    rec_kernel<<<B_, 512, 0, stream>>>(q_data, qa_data, Mv0, Wsm, Sq, dqv, E, A,
                                       WsrT, bs, Wab, bab, out);
}